// Round 4
// baseline (437.797 us; speedup 1.0000x reference)
//
#include <hip/hip_runtime.h>

#define T_SEQ 512
#define INPUT 14
#define HID 8
#define TC 16
#define NCHUNK (T_SEQ / TC)
#define BN_EPS 1e-5f

typedef float v2f __attribute__((ext_vector_type(2)));

__device__ __forceinline__ float fast_exp2(float x) { return __builtin_amdgcn_exp2f(x); }
__device__ __forceinline__ float fast_rcp(float x)  { return __builtin_amdgcn_rcpf(x); }

// packed fp32 math (CDNA): one instruction, two FMAs per lane
__device__ __forceinline__ v2f pk_fma(v2f a, v2f b, v2f c) {
    v2f d;
    asm("v_pk_fma_f32 %0, %1, %2, %3" : "=v"(d) : "v"(a), "v"(b), "v"(c));
    return d;
}
__device__ __forceinline__ v2f pk_add(v2f a, v2f b) {
    v2f d;
    asm("v_pk_add_f32 %0, %1, %2" : "=v"(d) : "v"(a), "v"(b));
    return d;
}

// ds_swizzle (LDS crossbar): BitMode imm = xor<<10 | or<<5 | and (and=0x1F confines to 32 lanes)
template <int IMM>
__device__ __forceinline__ float swz(float v) {
    return __int_as_float(__builtin_amdgcn_ds_swizzle(__float_as_int(v), IMM));
}

// DPP cross-lane ops (VALU pipe), all confined within 16-lane rows / quads
#define DPP_BC0  0x00   // quad_perm [0,0,0,0] : broadcast gate i
#define DPP_BC1  0x55   // quad_perm [1,1,1,1] : broadcast gate f
#define DPP_BC2  0xAA   // quad_perm [2,2,2,2] : broadcast gate g
#define DPP_BC3  0xFF   // quad_perm [3,3,3,3] : broadcast gate o
#define DPP_XOR8 0x128  // row_ror:8 : lane ^= 8 within 16-row
template <int CTRL>
__device__ __forceinline__ float dpp(float v) {
    return __int_as_float(__builtin_amdgcn_update_dpp(
        0, __float_as_int(v), CTRL, 0xF, 0xF, true));
}

// Butterfly images of h over unit bits (lane bits 2..4), paired {h,x8},{x4,x12},
// {x16,x24},{x20,x28}: pair units are u^{0,2},{1,3},{4,6},{5,7}.
__device__ __forceinline__ void butterfly8v(float h, v2f (&hx)[4]) {
    float x8  = dpp<DPP_XOR8>(h);  // xor 8  (VALU)
    float x4  = swz<0x101F>(h);    // xor 4  (LDS crossbar)
    float x16 = swz<0x401F>(h);    // xor 16
    float x20 = swz<0x501F>(h);    // xor 20
    hx[0].x = h;   hx[0].y = x8;
    hx[1].x = x4;  hx[1].y = dpp<DPP_XOR8>(x4);   // xor 12
    hx[2].x = x16; hx[2].y = dpp<DPP_XOR8>(x16);  // xor 24
    hx[3].x = x20; hx[3].y = dpp<DPP_XOR8>(x20);  // xor 28
}

// ============================================================================
// LAYER-PIPELINED HALF-WAVE STRUCTURE
// Block: 256 threads = 4 waves; each wave handles ONE batch element.
//   lanes  0-31 (half 0): layer-1 gates for timestep t      (= wave-step s)
//   lanes 32-63 (half 1): layer-2 gates for timestep t-1    (skew-1 pipeline)
// Both halves run the SAME instruction stream:
//   acc = xp[t] + dotA(own h images, WA) + dotB(swapped images, WB)
// with per-lane operands: half0: xp=Wih1*x+b1, WA=Whh1, WB=0
//                         half1: xp=bias2 (x-weights zeroed), WA=Whh2, WB=Wih2
// h1(t) images cross the half boundary via __shfl_xor(.,32) at step end.
// This doubles wave count (4096 -> 4 waves/SIMD) and halves the per-step
// serial chain (one layer per wave-step).
// Numerics: weights/biases pre-scaled by the lane's exp2 activation constant;
// cell state kept pre-scaled (C = -2.885*c).
// ============================================================================
__global__ __launch_bounds__(256, 4)
void lstm_forex_kernel(const float* __restrict__ x,
                       const float* __restrict__ Wih1, const float* __restrict__ Whh1,
                       const float* __restrict__ bih1, const float* __restrict__ bhh1,
                       const float* __restrict__ Wih2, const float* __restrict__ Whh2,
                       const float* __restrict__ bih2, const float* __restrict__ bhh2,
                       const float* __restrict__ bn_gamma, const float* __restrict__ bn_beta,
                       const float* __restrict__ bn_mean, const float* __restrict__ bn_var,
                       const float* __restrict__ w1p, const float* __restrict__ b1p,
                       const float* __restrict__ w2p, const float* __restrict__ b2p,
                       float* __restrict__ out)
{
    __shared__ float xbuf[4][TC][16];   // [wave][t][14 padded to 16]

    const int tid  = threadIdx.x;
    const int wave = tid >> 6;
    const int lane = tid & 63;
    const int half = lane >> 5;          // 0: layer-1 lanes, 1: layer-2 lanes
    const int l5   = lane & 31;
    const int u    = (l5 >> 2) & 7;      // unit
    const int type = l5 & 3;             // gate type (0=i,1=f,2=g,3=o)
    const int row  = type * 8 + u;       // weight row (PyTorch i,f,g,o blocks)

    const int b = blockIdx.x * 4 + wave; // one element per wave

    // exp2-domain activation constants (same for both halves/layers)
    const float gateScale = (type == 2) ? -2.885390082f : -1.4426950408f;
    const float actMul    = (type == 2) ? -5.770780164f : 1.f;
    const float actAdd    = (type == 2) ?  2.885390082f : 0.f;

    // ---- per-lane weights: half-dependent role selection ----
    const float xScale = half ? 0.f : gateScale;          // x-proj weights zeroed for half1
    const float bScale = half ? gateScale : 0.f;          // dotB weights zeroed for half0
    const float* WA    = half ? Whh2 : Whh1;              // own-recurrent matrix

    v2f wi1p[7], wAv[4], wBv[4];
#pragma unroll
    for (int k = 0; k < 7; ++k) {
        wi1p[k].x = Wih1[row * INPUT + 2 * k]     * xScale;
        wi1p[k].y = Wih1[row * INPUT + 2 * k + 1] * xScale;
    }
    const int poff[4] = {0, 1, 4, 5};
#pragma unroll
    for (int p = 0; p < 4; ++p) {
        int j0 = u ^ poff[p], j1 = j0 ^ 2;
        wAv[p].x = WA[row * HID + j0] * gateScale;
        wAv[p].y = WA[row * HID + j1] * gateScale;
        wBv[p].x = Wih2[row * HID + j0] * bScale;
        wBv[p].y = Wih2[row * HID + j1] * bScale;
    }
    const float bs = (half ? (bih2[row] + bhh2[row]) : (bih1[row] + bhh1[row])) * gateScale;
    const v2f biasv = { bs, 0.f };

    // ---- x staging: 224 dwords per wave-chunk (16 t * 14), 4 iters, last half-masked ----
    const float* gptr[4];
    int loff[4];
#pragma unroll
    for (int it = 0; it < 4; ++it) {
        int d  = it * 64 + lane;
        int dc = d < 224 ? d : 223;       // clamp (guarded below anyway)
        int tr = dc / 14;
        int k  = dc - tr * 14;
        gptr[it] = x + (size_t)b * (T_SEQ * INPUT) + dc;
        loff[it] = tr * 16 + k;
    }
    const bool v3 = lane < 32;            // validity of the 4th staging slot

    v2f hA[4], vB[4];                     // own butterfly images; swapped images
    float cc = 0.f;                       // pre-scaled cell state (own layer)
#pragma unroll
    for (int p = 0; p < 4; ++p) { hA[p] = (v2f){0.f, 0.f}; vB[p] = (v2f){0.f, 0.f}; }

    // prefetch chunk 0
    float st[4];
#pragma unroll
    for (int it = 0; it < 4; ++it)
        if (it < 3 || v3) { st[it] = *gptr[it]; gptr[it] += TC * INPUT; }

    float (*xw)[16] = xbuf[wave];

    for (int c = 0; c < NCHUNK; ++c) {
        // stage chunk c (per-wave buffer; in-order DS per wave makes it visible below)
#pragma unroll
        for (int it = 0; it < 4; ++it)
            if (it < 3 || v3) ((float*)xw)[loff[it]] = st[it];
        if (c + 1 < NCHUNK) {
#pragma unroll
            for (int it = 0; it < 4; ++it)
                if (it < 3 || v3) { st[it] = *gptr[it]; gptr[it] += TC * INPUT; }
        }
        __builtin_amdgcn_wave_barrier();

#pragma unroll
        for (int t = 0; t < TC; ++t) {
            // x row broadcast to all 64 lanes (same address -> LDS broadcast)
            const v2f* xv = (const v2f*)&xw[t][0];
            v2f x0 = xv[0], x1 = xv[1], x2 = xv[2], x3 = xv[3];
            v2f x4 = xv[4], x5 = xv[5], x6 = xv[6];

            // xp: real L1 x-projection on half0; degenerates to {bias2,0} on half1
            v2f s0 = pk_fma(x0, wi1p[0], biasv);
            v2f s1 = pk_fma(x1, wi1p[1], (v2f){0.f, 0.f});
            s0 = pk_fma(x2, wi1p[2], s0);
            s1 = pk_fma(x3, wi1p[3], s1);
            s0 = pk_fma(x4, wi1p[4], s0);
            s1 = pk_fma(x5, wi1p[5], s1);
            s0 = pk_fma(x6, wi1p[6], s0);

            // dotA: own recurrent (h1(t-1) for half0, h2(t-2) for half1)
            s0 = pk_fma(hA[0], wAv[0], s0);
            s1 = pk_fma(hA[1], wAv[1], s1);
            s0 = pk_fma(hA[2], wAv[2], s0);
            s1 = pk_fma(hA[3], wAv[3], s1);
            // dotB: swapped images (h1(t-1) images for half1; zero weights on half0)
            s0 = pk_fma(vB[0], wBv[0], s0);
            s1 = pk_fma(vB[1], wBv[1], s1);
            s0 = pk_fma(vB[2], wBv[2], s0);
            s1 = pk_fma(vB[3], wBv[3], s1);
            v2f sC = pk_add(s0, s1);
            float acc = sC.x + sC.y;

            // own-gate activation
            float v0 = fmaf(fast_rcp(1.f + fast_exp2(acc)), actMul, actAdd);
            float vi = dpp<DPP_BC0>(v0);
            float vf = dpp<DPP_BC1>(v0);
            float vg = dpp<DPP_BC2>(v0);   // = -2.885*tanh(g)
            float vo = dpp<DPP_BC3>(v0);
            cc = fmaf(vf, cc, vi * vg);
            float th = fmaf(fast_rcp(1.f + fast_exp2(cc)), 2.f, -1.f);
            float hnew = vo * th;          // h1(t) on half0, h2(t-1) on half1
            butterfly8v(hnew, hA);

            // pipeline-start fix: half1's s=0 output is garbage (h2(-1) must be 0)
            if (c == 0 && t == 0) {
                if (half) {
#pragma unroll
                    for (int p = 0; p < 4; ++p) hA[p] = (v2f){0.f, 0.f};
                    cc = 0.f;
                }
            }

            // cross-half image transfer: half1 receives half0's h1(t) images
            // (half0 receives half1's images -- multiplied by zero weights)
#pragma unroll
            for (int p = 0; p < 4; ++p) {
                vB[p].x = __shfl_xor(hA[p].x, 32);
                vB[p].y = __shfl_xor(hA[p].y, 32);
            }
        }
    }

    // ---- pipeline drain: one extra step so half1 computes L2 for t=511 ----
    {
        v2f s0 = biasv, s1 = (v2f){0.f, 0.f};
        s0 = pk_fma(hA[0], wAv[0], s0);
        s1 = pk_fma(hA[1], wAv[1], s1);
        s0 = pk_fma(hA[2], wAv[2], s0);
        s1 = pk_fma(hA[3], wAv[3], s1);
        s0 = pk_fma(vB[0], wBv[0], s0);
        s1 = pk_fma(vB[1], wBv[1], s1);
        s0 = pk_fma(vB[2], wBv[2], s0);
        s1 = pk_fma(vB[3], wBv[3], s1);
        v2f sC = pk_add(s0, s1);
        float acc = sC.x + sC.y;

        float v0 = fmaf(fast_rcp(1.f + fast_exp2(acc)), actMul, actAdd);
        float vi = dpp<DPP_BC0>(v0);
        float vf = dpp<DPP_BC1>(v0);
        float vg = dpp<DPP_BC2>(v0);
        float vo = dpp<DPP_BC3>(v0);
        cc = fmaf(vf, cc, vi * vg);
        float th = fmaf(fast_rcp(1.f + fast_exp2(cc)), 2.f, -1.f);
        float hnew = vo * th;              // h2(511) on half1
        butterfly8v(hnew, hA);
    }

    // ---- BN (eval) + MLP head: lane 32 (half1, u=0, type=0) holds h2(511) images ----
    // pairs hold units {0,2},{1,3},{4,6},{5,7}
    if (lane == 32) {
        float h2v[HID];
        h2v[0] = hA[0].x; h2v[2] = hA[0].y;
        h2v[1] = hA[1].x; h2v[3] = hA[1].y;
        h2v[4] = hA[2].x; h2v[6] = hA[2].y;
        h2v[5] = hA[3].x; h2v[7] = hA[3].y;
        float nd[HID];
#pragma unroll
        for (int j = 0; j < HID; ++j) {
            float inv = 1.f / sqrtf(bn_var[j] + BN_EPS);
            nd[j] = bn_gamma[j] * (h2v[j] - bn_mean[j]) * inv + bn_beta[j];
        }
        float acc = b2p[0];
#pragma unroll
        for (int m = 0; m < 4; ++m) {
            float s = b1p[m];
#pragma unroll
            for (int j = 0; j < HID; ++j) s = fmaf(nd[j], w1p[m * HID + j], s);
            s = fmaxf(s, 0.f);
            acc = fmaf(s, w2p[m], acc);
        }
        out[b] = acc;
    }
}

extern "C" void kernel_launch(void* const* d_in, const int* in_sizes, int n_in,
                              void* d_out, int out_size, void* d_ws, size_t ws_size,
                              hipStream_t stream) {
    const float* x        = (const float*)d_in[0];
    const float* Wih1     = (const float*)d_in[1];
    const float* Whh1     = (const float*)d_in[2];
    const float* bih1     = (const float*)d_in[3];
    const float* bhh1     = (const float*)d_in[4];
    const float* Wih2     = (const float*)d_in[5];
    const float* Whh2     = (const float*)d_in[6];
    const float* bih2     = (const float*)d_in[7];
    const float* bhh2     = (const float*)d_in[8];
    const float* bn_gamma = (const float*)d_in[9];
    const float* bn_beta  = (const float*)d_in[10];
    const float* bn_mean  = (const float*)d_in[11];
    const float* bn_var   = (const float*)d_in[12];
    const float* w1p      = (const float*)d_in[13];
    const float* b1p      = (const float*)d_in[14];
    const float* w2p      = (const float*)d_in[15];
    const float* b2p      = (const float*)d_in[16];
    float* out = (float*)d_out;

    const int B = in_sizes[0] / (T_SEQ * INPUT);   // 4096
    dim3 grid(B / 4), block(256);
    hipLaunchKernelGGL(lstm_forex_kernel, grid, block, 0, stream,
                       x, Wih1, Whh1, bih1, bhh1, Wih2, Whh2, bih2, bhh2,
                       bn_gamma, bn_beta, bn_mean, bn_var, w1p, b1p, w2p, b2p, out);
}

// Round 6
// 359.003 us; speedup vs baseline: 1.2195x; 1.2195x over previous
//
#include <hip/hip_runtime.h>

#define T_SEQ 512
#define INPUT 14
#define HID 8
#define TC 16
#define NCHUNK (T_SEQ / TC)
#define BN_EPS 1e-5f

typedef float v2f __attribute__((ext_vector_type(2)));

__device__ __forceinline__ float fast_exp2(float x) { return __builtin_amdgcn_exp2f(x); }
__device__ __forceinline__ float fast_rcp(float x)  { return __builtin_amdgcn_rcpf(x); }

// packed fp32 math (CDNA): one instruction, two FMAs per lane
__device__ __forceinline__ v2f pk_fma(v2f a, v2f b, v2f c) {
    v2f d;
    asm("v_pk_fma_f32 %0, %1, %2, %3" : "=v"(d) : "v"(a), "v"(b), "v"(c));
    return d;
}
__device__ __forceinline__ v2f pk_add(v2f a, v2f b) {
    v2f d;
    asm("v_pk_add_f32 %0, %1, %2" : "=v"(d) : "v"(a), "v"(b));
    return d;
}

// ds_swizzle (LDS crossbar): BitMode imm = xor<<10 | or<<5 | and (and=0x1F confines to 32 lanes)
template <int IMM>
__device__ __forceinline__ float swz(float v) {
    return __int_as_float(__builtin_amdgcn_ds_swizzle(__float_as_int(v), IMM));
}

// DPP cross-lane ops (VALU pipe), all confined within 16-lane rows / quads
#define DPP_BC0  0x00   // quad_perm [0,0,0,0] : broadcast gate i
#define DPP_BC1  0x55   // quad_perm [1,1,1,1] : broadcast gate f
#define DPP_BC2  0xAA   // quad_perm [2,2,2,2] : broadcast gate g
#define DPP_BC3  0xFF   // quad_perm [3,3,3,3] : broadcast gate o
#define DPP_XOR8 0x128  // row_ror:8 : lane ^= 8 within 16-row
template <int CTRL>
__device__ __forceinline__ float dpp(float v) {
    return __int_as_float(__builtin_amdgcn_update_dpp(
        0, __float_as_int(v), CTRL, 0xF, 0xF, true));
}

// Cross-half exchange on the VALU pipe: returns h[lane ^ 32].
// v_permlane32_swap_b32 with both operands = h yields {own, lane^32} at every lane
// in SOME order (direction convention-independent), so r0 ^ r1 ^ h = h[lane^32].
// NOTE: builtin returns an ext_vector uint2 -- element access via [], not .x/.y.
__device__ __forceinline__ float xor32(float h) {
    unsigned hb = __float_as_uint(h);
    auto r = __builtin_amdgcn_permlane32_swap(hb, hb, false, false);
    return __uint_as_float(r[0] ^ r[1] ^ hb);
}

// Butterfly images of h over unit bits (lane bits 2..4), paired {h,x8},{x4,x12},
// {x16,x24},{x20,x28}: pair units are u^{0,2},{1,3},{4,6},{5,7}.
__device__ __forceinline__ void butterfly8v(float h, v2f (&hx)[4]) {
    float x8  = dpp<DPP_XOR8>(h);  // xor 8  (VALU)
    float x4  = swz<0x101F>(h);    // xor 4  (LDS crossbar)
    float x16 = swz<0x401F>(h);    // xor 16
    float x20 = swz<0x501F>(h);    // xor 20
    hx[0].x = h;   hx[0].y = x8;
    hx[1].x = x4;  hx[1].y = dpp<DPP_XOR8>(x4);   // xor 12
    hx[2].x = x16; hx[2].y = dpp<DPP_XOR8>(x16);  // xor 24
    hx[3].x = x20; hx[3].y = dpp<DPP_XOR8>(x20);  // xor 28
}

// ============================================================================
// LAYER-PIPELINED HALF-WAVE STRUCTURE with VALU-only half exchange
// Block: 256 threads = 4 waves; each wave handles ONE batch element.
//   lanes  0-31 (half 0): layer-1 gates for timestep t      (= wave-step s)
//   lanes 32-63 (half 1): layer-2 gates for timestep t-1    (skew-1 pipeline)
// Both halves run the SAME instruction stream:
//   acc = xp[t] + dotA(own h images, WA) + dotB(swapped images, WB)
// with per-lane operands: half0: xp=Wih1*x+b1, WA=Whh1, WB=0
//                         half1: xp=bias2 (x-weights zeroed), WA=Whh2, WB=Wih2
// h1(t) crosses the half boundary as a SCALAR via permlane32_swap (VALU, no DS),
// then a second butterfly rebuilds its image set on half1's lanes.
// Numerics: weights/biases pre-scaled by the lane's exp2 activation constant;
// cell state kept pre-scaled (C = -2.885*c).
// ============================================================================
__global__ __launch_bounds__(256, 4)
void lstm_forex_kernel(const float* __restrict__ x,
                       const float* __restrict__ Wih1, const float* __restrict__ Whh1,
                       const float* __restrict__ bih1, const float* __restrict__ bhh1,
                       const float* __restrict__ Wih2, const float* __restrict__ Whh2,
                       const float* __restrict__ bih2, const float* __restrict__ bhh2,
                       const float* __restrict__ bn_gamma, const float* __restrict__ bn_beta,
                       const float* __restrict__ bn_mean, const float* __restrict__ bn_var,
                       const float* __restrict__ w1p, const float* __restrict__ b1p,
                       const float* __restrict__ w2p, const float* __restrict__ b2p,
                       float* __restrict__ out)
{
    __shared__ float xbuf[4][TC][16];   // [wave][t][14 padded to 16]

    const int tid  = threadIdx.x;
    const int wave = tid >> 6;
    const int lane = tid & 63;
    const int half = lane >> 5;          // 0: layer-1 lanes, 1: layer-2 lanes
    const int l5   = lane & 31;
    const int u    = (l5 >> 2) & 7;      // unit
    const int type = l5 & 3;             // gate type (0=i,1=f,2=g,3=o)
    const int row  = type * 8 + u;       // weight row (PyTorch i,f,g,o blocks)

    const int b = blockIdx.x * 4 + wave; // one element per wave

    // exp2-domain activation constants (same for both halves/layers)
    const float gateScale = (type == 2) ? -2.885390082f : -1.4426950408f;
    const float actMul    = (type == 2) ? -5.770780164f : 1.f;
    const float actAdd    = (type == 2) ?  2.885390082f : 0.f;

    // ---- per-lane weights: half-dependent role selection ----
    const float xScale = half ? 0.f : gateScale;          // x-proj weights zeroed for half1
    const float bScale = half ? gateScale : 0.f;          // dotB weights zeroed for half0
    const float* WA    = half ? Whh2 : Whh1;              // own-recurrent matrix

    v2f wi1p[7], wAv[4], wBv[4];
#pragma unroll
    for (int k = 0; k < 7; ++k) {
        wi1p[k].x = Wih1[row * INPUT + 2 * k]     * xScale;
        wi1p[k].y = Wih1[row * INPUT + 2 * k + 1] * xScale;
    }
    const int poff[4] = {0, 1, 4, 5};
#pragma unroll
    for (int p = 0; p < 4; ++p) {
        int j0 = u ^ poff[p], j1 = j0 ^ 2;
        wAv[p].x = WA[row * HID + j0] * gateScale;
        wAv[p].y = WA[row * HID + j1] * gateScale;
        wBv[p].x = Wih2[row * HID + j0] * bScale;
        wBv[p].y = Wih2[row * HID + j1] * bScale;
    }
    const float bs = (half ? (bih2[row] + bhh2[row]) : (bih1[row] + bhh1[row])) * gateScale;
    const v2f biasv = { bs, 0.f };

    // ---- x staging: 224 dwords per wave-chunk (16 t * 14), 4 iters, last half-masked ----
    const float* gptr[4];
    int loff[4];
#pragma unroll
    for (int it = 0; it < 4; ++it) {
        int d  = it * 64 + lane;
        int dc = d < 224 ? d : 223;       // clamp (guarded below anyway)
        int tr = dc / 14;
        int k  = dc - tr * 14;
        gptr[it] = x + (size_t)b * (T_SEQ * INPUT) + dc;
        loff[it] = tr * 16 + k;
    }
    const bool v3 = lane < 32;            // validity of the 4th staging slot

    v2f hA[4], vB[4];                     // own butterfly images; swapped images
    float cc = 0.f;                       // pre-scaled cell state (own layer)
#pragma unroll
    for (int p = 0; p < 4; ++p) { hA[p] = (v2f){0.f, 0.f}; vB[p] = (v2f){0.f, 0.f}; }

    // prefetch chunk 0
    float st[4];
#pragma unroll
    for (int it = 0; it < 4; ++it)
        if (it < 3 || v3) { st[it] = *gptr[it]; gptr[it] += TC * INPUT; }

    float (*xw)[16] = xbuf[wave];

    for (int c = 0; c < NCHUNK; ++c) {
        // stage chunk c (per-wave buffer; in-order DS per wave makes it visible below)
#pragma unroll
        for (int it = 0; it < 4; ++it)
            if (it < 3 || v3) ((float*)xw)[loff[it]] = st[it];
        if (c + 1 < NCHUNK) {
#pragma unroll
            for (int it = 0; it < 4; ++it)
                if (it < 3 || v3) { st[it] = *gptr[it]; gptr[it] += TC * INPUT; }
        }
        __builtin_amdgcn_wave_barrier();

#pragma unroll
        for (int t = 0; t < TC; ++t) {
            // x row broadcast to all 64 lanes (same address -> LDS broadcast)
            const v2f* xv = (const v2f*)&xw[t][0];
            v2f x0 = xv[0], x1 = xv[1], x2 = xv[2], x3 = xv[3];
            v2f x4 = xv[4], x5 = xv[5], x6 = xv[6];

            // xp: real L1 x-projection on half0; degenerates to {bias2,0} on half1
            v2f s0 = pk_fma(x0, wi1p[0], biasv);
            v2f s1 = pk_fma(x1, wi1p[1], (v2f){0.f, 0.f});
            s0 = pk_fma(x2, wi1p[2], s0);
            s1 = pk_fma(x3, wi1p[3], s1);
            s0 = pk_fma(x4, wi1p[4], s0);
            s1 = pk_fma(x5, wi1p[5], s1);
            s0 = pk_fma(x6, wi1p[6], s0);

            // dotA: own recurrent (h1(t-1) for half0, h2(t-2) for half1)
            s0 = pk_fma(hA[0], wAv[0], s0);
            s1 = pk_fma(hA[1], wAv[1], s1);
            s0 = pk_fma(hA[2], wAv[2], s0);
            s1 = pk_fma(hA[3], wAv[3], s1);
            // dotB: swapped images (h1(t-1) images for half1; zero weights on half0)
            s0 = pk_fma(vB[0], wBv[0], s0);
            s1 = pk_fma(vB[1], wBv[1], s1);
            s0 = pk_fma(vB[2], wBv[2], s0);
            s1 = pk_fma(vB[3], wBv[3], s1);
            v2f sC = pk_add(s0, s1);
            float acc = sC.x + sC.y;

            // own-gate activation
            float v0 = fmaf(fast_rcp(1.f + fast_exp2(acc)), actMul, actAdd);
            float vi = dpp<DPP_BC0>(v0);
            float vf = dpp<DPP_BC1>(v0);
            float vg = dpp<DPP_BC2>(v0);   // = -2.885*tanh(g)
            float vo = dpp<DPP_BC3>(v0);
            cc = fmaf(vf, cc, vi * vg);
            float th = fmaf(fast_rcp(1.f + fast_exp2(cc)), 2.f, -1.f);
            float hnew = vo * th;          // h1(t) on half0, h2(t-1) on half1

            // own images for next step's dotA
            butterfly8v(hnew, hA);
            // cross-half transfer: scalar permlane32_swap (VALU), then rebuild
            // half0's image set on half1's lanes (butterfly confined to 32 lanes)
            float hswap = xor32(hnew);
            butterfly8v(hswap, vB);

            // pipeline-start fix: half1's s=0 output is garbage (h2(-1) must be 0)
            if (c == 0 && t == 0) {
                if (half) {
#pragma unroll
                    for (int p = 0; p < 4; ++p) hA[p] = (v2f){0.f, 0.f};
                    cc = 0.f;
                }
            }
        }
    }

    // ---- pipeline drain: one extra step so half1 computes L2 for t=511 ----
    {
        v2f s0 = biasv, s1 = (v2f){0.f, 0.f};
        s0 = pk_fma(hA[0], wAv[0], s0);
        s1 = pk_fma(hA[1], wAv[1], s1);
        s0 = pk_fma(hA[2], wAv[2], s0);
        s1 = pk_fma(hA[3], wAv[3], s1);
        s0 = pk_fma(vB[0], wBv[0], s0);
        s1 = pk_fma(vB[1], wBv[1], s1);
        s0 = pk_fma(vB[2], wBv[2], s0);
        s1 = pk_fma(vB[3], wBv[3], s1);
        v2f sC = pk_add(s0, s1);
        float acc = sC.x + sC.y;

        float v0 = fmaf(fast_rcp(1.f + fast_exp2(acc)), actMul, actAdd);
        float vi = dpp<DPP_BC0>(v0);
        float vf = dpp<DPP_BC1>(v0);
        float vg = dpp<DPP_BC2>(v0);
        float vo = dpp<DPP_BC3>(v0);
        cc = fmaf(vf, cc, vi * vg);
        float th = fmaf(fast_rcp(1.f + fast_exp2(cc)), 2.f, -1.f);
        float hnew = vo * th;              // h2(511) on half1
        butterfly8v(hnew, hA);
    }

    // ---- BN (eval) + MLP head: lane 32 (half1, u=0, type=0) holds h2(511) images ----
    // pairs hold units {0,2},{1,3},{4,6},{5,7}
    if (lane == 32) {
        float h2v[HID];
        h2v[0] = hA[0].x; h2v[2] = hA[0].y;
        h2v[1] = hA[1].x; h2v[3] = hA[1].y;
        h2v[4] = hA[2].x; h2v[6] = hA[2].y;
        h2v[5] = hA[3].x; h2v[7] = hA[3].y;
        float nd[HID];
#pragma unroll
        for (int j = 0; j < HID; ++j) {
            float inv = 1.f / sqrtf(bn_var[j] + BN_EPS);
            nd[j] = bn_gamma[j] * (h2v[j] - bn_mean[j]) * inv + bn_beta[j];
        }
        float acc = b2p[0];
#pragma unroll
        for (int m = 0; m < 4; ++m) {
            float s = b1p[m];
#pragma unroll
            for (int j = 0; j < HID; ++j) s = fmaf(nd[j], w1p[m * HID + j], s);
            s = fmaxf(s, 0.f);
            acc = fmaf(s, w2p[m], acc);
        }
        out[b] = acc;
    }
}

extern "C" void kernel_launch(void* const* d_in, const int* in_sizes, int n_in,
                              void* d_out, int out_size, void* d_ws, size_t ws_size,
                              hipStream_t stream) {
    const float* x        = (const float*)d_in[0];
    const float* Wih1     = (const float*)d_in[1];
    const float* Whh1     = (const float*)d_in[2];
    const float* bih1     = (const float*)d_in[3];
    const float* bhh1     = (const float*)d_in[4];
    const float* Wih2     = (const float*)d_in[5];
    const float* Whh2     = (const float*)d_in[6];
    const float* bih2     = (const float*)d_in[7];
    const float* bhh2     = (const float*)d_in[8];
    const float* bn_gamma = (const float*)d_in[9];
    const float* bn_beta  = (const float*)d_in[10];
    const float* bn_mean  = (const float*)d_in[11];
    const float* bn_var   = (const float*)d_in[12];
    const float* w1p      = (const float*)d_in[13];
    const float* b1p      = (const float*)d_in[14];
    const float* w2p      = (const float*)d_in[15];
    const float* b2p      = (const float*)d_in[16];
    float* out = (float*)d_out;

    const int B = in_sizes[0] / (T_SEQ * INPUT);   // 4096
    dim3 grid(B / 4), block(256);
    hipLaunchKernelGGL(lstm_forex_kernel, grid, block, 0, stream,
                       x, Wih1, Whh1, bih1, bhh1, Wih2, Whh2, bih2, bhh2,
                       bn_gamma, bn_beta, bn_mean, bn_var, w1p, b1p, w2p, b2p, out);
}

// Round 7
// 357.069 us; speedup vs baseline: 1.2261x; 1.0054x over previous
//
#include <hip/hip_runtime.h>

#define T_SEQ 512
#define INPUT 14
#define HID 8
#define TC 16
#define NCHUNK (T_SEQ / TC)
#define BN_EPS 1e-5f

typedef float v2f __attribute__((ext_vector_type(2)));

__device__ __forceinline__ float fast_exp2(float x) { return __builtin_amdgcn_exp2f(x); }
__device__ __forceinline__ float fast_rcp(float x)  { return __builtin_amdgcn_rcpf(x); }

// packed fp32 math (CDNA): one instruction, two FMAs per lane (2-pass, 4cy issue)
__device__ __forceinline__ v2f pk_fma(v2f a, v2f b, v2f c) {
    v2f d;
    asm("v_pk_fma_f32 %0, %1, %2, %3" : "=v"(d) : "v"(a), "v"(b), "v"(c));
    return d;
}
__device__ __forceinline__ v2f pk_mul(v2f a, v2f b) {
    v2f d;
    asm("v_pk_mul_f32 %0, %1, %2" : "=v"(d) : "v"(a), "v"(b));
    return d;
}
__device__ __forceinline__ v2f pk_add(v2f a, v2f b) {
    v2f d;
    asm("v_pk_add_f32 %0, %1, %2" : "=v"(d) : "v"(a), "v"(b));
    return d;
}

// ds_swizzle fallback only (BitMode imm = xor<<10 | or<<5 | and)
template <int IMM>
__device__ __forceinline__ float swz(float v) {
    return __int_as_float(__builtin_amdgcn_ds_swizzle(__float_as_int(v), IMM));
}

// DPP controls (VALU pipe)
#define DPP_QP1   0xB1   // quad_perm [1,0,3,2] : lane ^= 1 within quad
#define DPP_QP2   0x4E   // quad_perm [2,3,0,1] : lane ^= 2
#define DPP_QP3   0x1B   // quad_perm [3,2,1,0] : lane ^= 3
#define DPP_ROR4  0x124  // row rotate by 4 within 16-row (direction probed)
#define DPP_ROR8  0x128  // row rotate by 8 = lane ^= 8 (direction-symmetric)
#define DPP_ROR12 0x12C  // row rotate by 12 (opposite of ror4)
template <int CTRL>
__device__ __forceinline__ float dpp(float v) {
    return __int_as_float(__builtin_amdgcn_update_dpp(
        0, __float_as_int(v), CTRL, 0xF, 0xF, true));
}
template <int CTRL>
__device__ __forceinline__ int dpp_i(int v) {
    return __builtin_amdgcn_update_dpp(0, v, CTRL, 0xF, 0xF, true);
}

// lane ^= 16 on the VALU pipe (direction-proof: {r0,r1} = {own, lane^16} in some
// order, so r0^r1^h = h[lane^16]). Falls back to LDS swizzle if builtin missing.
__device__ __forceinline__ float xor16v(float h) {
#if __has_builtin(__builtin_amdgcn_permlane16_swap)
    unsigned hb = __float_as_uint(h);
    auto r = __builtin_amdgcn_permlane16_swap(hb, hb, false, false);
    return __uint_as_float(r[0] ^ r[1] ^ hb);
#else
    return swz<0x401F>(h);
#endif
}

// ============================================================================
// DS-FREE LANE LAYOUT (within each 32-lane element group):
//   unit u (0..7)  = (l5 & 3) | ((l5 >> 2) & 4)    -- lane bits {0,1,4}
//   type t (0..3)  = (l5 >> 2) & 3                 -- lane bits {2,3}  (i,f,g,o)
//   weight row     = t*8 + u
// Butterfly images of h over unit-xor m (all VALU, zero DS):
//   m=1,2,3 : quad_perm (lane bits 0,1); m=4 : xor16v (lane bit 4); m=5,6,7 :
//   quad_perm of the xor16 image.  Pairs hx[p] = {h[u^(2p)], h[u^(2p+1)]}.
// Gate combine: row_ror:4/8/12 rotate the type field (unit bits preserved).
//   ror:8 is direction-symmetric; ror4/ror12 direction resolved by a one-time
//   lane-id probe (correct under either hardware rotation convention).
// Numerics: weights/biases pre-scaled by the lane's exp2 activation constant;
// cell state kept pre-scaled (C = -2.885*c) so tanh(c)=2*rcp(1+exp2(C))-1.
// Block: 256 threads = 4 waves; each wave = 2 batch elements (32 lanes each).
// ============================================================================
__global__ __launch_bounds__(256, 2)
void lstm_forex_kernel(const float* __restrict__ x,
                       const float* __restrict__ Wih1, const float* __restrict__ Whh1,
                       const float* __restrict__ bih1, const float* __restrict__ bhh1,
                       const float* __restrict__ Wih2, const float* __restrict__ Whh2,
                       const float* __restrict__ bih2, const float* __restrict__ bhh2,
                       const float* __restrict__ bn_gamma, const float* __restrict__ bn_beta,
                       const float* __restrict__ bn_mean, const float* __restrict__ bn_var,
                       const float* __restrict__ w1p, const float* __restrict__ b1p,
                       const float* __restrict__ w2p, const float* __restrict__ b2p,
                       float* __restrict__ out)
{
    __shared__ float xbuf[4][2][TC][16];   // [wave][elem][t][14 padded to 16]

    const int tid  = threadIdx.x;
    const int wave = tid >> 6;
    const int lane = tid & 63;
    const int grp  = lane >> 5;          // which of the wave's 2 batch elements
    const int l5   = lane & 31;
    const int u    = (l5 & 3) | ((l5 >> 2) & 4);   // unit: lane bits {0,1,4}
    const int type = (l5 >> 2) & 3;                // gate type: lane bits {2,3}
    const int row  = type * 8 + u;       // weight row (PyTorch i,f,g,o blocks)
    const bool tb0 = (type & 1) != 0;
    const bool tb1 = (type & 2) != 0;

    const int b = blockIdx.x * 8 + wave * 2 + grp;

    // one-time direction probe for row_ror:4 (dst i = src (i+4)&15, or (i-4)&15)
    const int got   = dpp_i<DPP_ROR4>(l5);
    const bool dplus = (got == ((l5 & 16) | ((l5 + 4) & 15)));

    // exp2-domain activation constants; scale folded into weights below
    const float gateScale = (type == 2) ? -2.885390082f : -1.4426950408f;
    const float actMul    = (type == 2) ? -5.770780164f : 1.f;   // g-lane -> -2.885*tanh(g)
    const float actAdd    = (type == 2) ?  2.885390082f : 0.f;

    // ---- per-lane weight rows (pre-scaled); recurrent mats pre-permuted for the
    //      XOR butterfly, paired {u^0,u^1},{u^2,u^3},{u^4,u^5},{u^6,u^7} ----
    v2f wi1p[7], wh1v[4], wi2v[4], wh2v[4];
#pragma unroll
    for (int k = 0; k < 7; ++k) {
        wi1p[k].x = Wih1[row * INPUT + 2 * k]     * gateScale;
        wi1p[k].y = Wih1[row * INPUT + 2 * k + 1] * gateScale;
    }
#pragma unroll
    for (int p = 0; p < 4; ++p) {
        int j0 = u ^ (2 * p), j1 = j0 ^ 1;
        wh1v[p].x = Whh1[row * HID + j0] * gateScale;
        wh1v[p].y = Whh1[row * HID + j1] * gateScale;
        wi2v[p].x = Wih2[row * HID + j0] * gateScale;
        wi2v[p].y = Wih2[row * HID + j1] * gateScale;
        wh2v[p].x = Whh2[row * HID + j0] * gateScale;
        wh2v[p].y = Whh2[row * HID + j1] * gateScale;
    }
    const float bsum1s = (bih1[row] + bhh1[row]) * gateScale;
    const float bsum2s = (bih2[row] + bhh2[row]) * gateScale;
    const v2f   bias1  = { bsum1s, 0.f };
    const v2f   bias2  = { bsum2s, 0.f };

    // ---- x staging: 448 dwords per wave-chunk (2 elems * 16 t * 14), 7 per lane ----
    const float* gptr[7];
    int loff[7];
#pragma unroll
    for (int it = 0; it < 7; ++it) {
        int d   = it * 64 + lane;       // coalesced flat dword index within wave-chunk
        int es  = d / 224;              // which elem
        int idx = d - es * 224;         // dword within elem's 16x14 chunk
        int tr  = idx / 14;
        int k   = idx - tr * 14;
        int bb  = blockIdx.x * 8 + wave * 2 + es;
        gptr[it] = x + (size_t)bb * (T_SEQ * INPUT) + idx;
        loff[it] = es * (TC * 16) + tr * 16 + k;   // padded LDS layout
    }

    v2f hx1[4], hx2[4];                 // paired butterfly images of h1, h2
    float c1 = 0.f, c2 = 0.f;           // PRE-SCALED cell states (C = -2.885*c)
#pragma unroll
    for (int p = 0; p < 4; ++p) { hx1[p] = (v2f){0.f, 0.f}; hx2[p] = (v2f){0.f, 0.f}; }

    // prefetch chunk 0
    float st[7];
#pragma unroll
    for (int it = 0; it < 7; ++it) { st[it] = *gptr[it]; gptr[it] += TC * INPUT; }

    float (*xw)[TC][16] = xbuf[wave];

    for (int c = 0; c < NCHUNK; ++c) {
        // stage chunk c into LDS (in-order DS per wave makes this visible to reads below)
#pragma unroll
        for (int it = 0; it < 7; ++it) ((float*)xw)[loff[it]] = st[it];
        // prefetch chunk c+1 while computing chunk c
        if (c + 1 < NCHUNK) {
#pragma unroll
            for (int it = 0; it < 7; ++it) { st[it] = *gptr[it]; gptr[it] += TC * INPUT; }
        }
        __builtin_amdgcn_wave_barrier();

#pragma unroll
        for (int t = 0; t < TC; ++t) {
            const v2f* xv = (const v2f*)&xw[grp][t][0];
            v2f x0 = xv[0], x1 = xv[1], x2 = xv[2], x3 = xv[3];
            v2f x4 = xv[4], x5 = xv[5], x6 = xv[6];

            // ---- layer 1 x-projection (off critical path) ----
            v2f ax0 = pk_fma(x0, wi1p[0], bias1);
            v2f ax1 = pk_mul(x1, wi1p[1]);
            ax0 = pk_fma(x2, wi1p[2], ax0);
            ax1 = pk_fma(x3, wi1p[3], ax1);
            ax0 = pk_fma(x4, wi1p[4], ax0);
            ax1 = pk_fma(x5, wi1p[5], ax1);
            ax0 = pk_fma(x6, wi1p[6], ax0);

            // layer-2 recurrent part (h2 of previous step -- off chain)
            v2f qA = pk_fma(hx2[0], wh2v[0], bias2);
            v2f qB = pk_mul(hx2[1], wh2v[1]);
            qA = pk_fma(hx2[2], wh2v[2], qA);
            qB = pk_fma(hx2[3], wh2v[3], qB);

            // layer-1 recurrent butterfly dot
            v2f sA = pk_fma(hx1[0], wh1v[0], ax0);
            v2f sB = pk_fma(hx1[1], wh1v[1], ax1);
            sA = pk_fma(hx1[2], wh1v[2], sA);
            sB = pk_fma(hx1[3], wh1v[3], sB);
            v2f sC = pk_add(sA, sB);
            float acc = sC.x + sC.y;

            // own-gate activation (weights pre-scaled: no mul before exp2)
            float v0 = fmaf(fast_rcp(1.f + fast_exp2(acc)), actMul, actAdd);
            // gate combine via type-field rotations (all VALU)
            float r1 = dpp<DPP_ROR4>(v0);
            float r2 = dpp<DPP_ROR8>(v0);     // gate t+2 (direction-symmetric)
            float r3 = dpp<DPP_ROR12>(v0);
            float va = dplus ? r1 : r3;       // gate t+1
            float vb = dplus ? r3 : r1;       // gate t+3
            float m02 = v0 * r2;
            float m13 = va * vb;
            float P = tb0 ? m13 : m02;        // = sigmoid(i) * (-2.885*tanh(g))
            float sF1 = tb0 ? v0 : va;
            float sF2 = tb0 ? r2 : vb;
            float F = tb1 ? sF2 : sF1;        // sigmoid(f)
            float O = tb1 ? sF1 : sF2;        // sigmoid(o)
            c1 = fmaf(F, c1, P);              // scaled cell update
            float th1 = fmaf(fast_rcp(1.f + fast_exp2(c1)), 2.f, -1.f);
            float h1u = O * th1;              // every lane holds h1[own unit]
            butterfly: ;
            {
                float y1 = dpp<DPP_QP1>(h1u);
                float y2 = dpp<DPP_QP2>(h1u);
                float y3 = dpp<DPP_QP3>(h1u);
                float y16 = xor16v(h1u);
                hx1[0].x = h1u; hx1[0].y = y1;
                hx1[1].x = y2;  hx1[1].y = y3;
                hx1[2].x = y16; hx1[2].y = dpp<DPP_QP1>(y16);
                hx1[3].x = dpp<DPP_QP2>(y16); hx1[3].y = dpp<DPP_QP3>(y16);
            }

            // ---- layer 2 ----
            v2f pA = pk_fma(hx1[0], wi2v[0], qA);
            v2f pB = pk_fma(hx1[1], wi2v[1], qB);
            pA = pk_fma(hx1[2], wi2v[2], pA);
            pB = pk_fma(hx1[3], wi2v[3], pB);
            v2f pC = pk_add(pA, pB);
            float acc2 = pC.x + pC.y;

            float w0 = fmaf(fast_rcp(1.f + fast_exp2(acc2)), actMul, actAdd);
            float z1 = dpp<DPP_ROR4>(w0);
            float z2 = dpp<DPP_ROR8>(w0);
            float z3 = dpp<DPP_ROR12>(w0);
            float wa = dplus ? z1 : z3;
            float wb = dplus ? z3 : z1;
            float n02 = w0 * z2;
            float n13 = wa * wb;
            float P2 = tb0 ? n13 : n02;
            float tF1 = tb0 ? w0 : wa;
            float tF2 = tb0 ? z2 : wb;
            float F2 = tb1 ? tF2 : tF1;
            float O2 = tb1 ? tF1 : tF2;
            c2 = fmaf(F2, c2, P2);
            float th2 = fmaf(fast_rcp(1.f + fast_exp2(c2)), 2.f, -1.f);
            float h2u = O2 * th2;
            {
                float y1 = dpp<DPP_QP1>(h2u);
                float y2 = dpp<DPP_QP2>(h2u);
                float y3 = dpp<DPP_QP3>(h2u);
                float y16 = xor16v(h2u);
                hx2[0].x = h2u; hx2[0].y = y1;
                hx2[1].x = y2;  hx2[1].y = y3;
                hx2[2].x = y16; hx2[2].y = dpp<DPP_QP1>(y16);
                hx2[3].x = dpp<DPP_QP2>(y16); hx2[3].y = dpp<DPP_QP3>(y16);
            }
        }
    }

    // ---- BN (eval) + MLP head, one lane per batch element ----
    // At l5==0 (u==0, type==0): hx2[p] = {h2[2p], h2[2p+1]}.
    if (l5 == 0) {
        float h2v[HID];
        h2v[0] = hx2[0].x; h2v[1] = hx2[0].y;
        h2v[2] = hx2[1].x; h2v[3] = hx2[1].y;
        h2v[4] = hx2[2].x; h2v[5] = hx2[2].y;
        h2v[6] = hx2[3].x; h2v[7] = hx2[3].y;
        float nd[HID];
#pragma unroll
        for (int j = 0; j < HID; ++j) {
            float inv = 1.f / sqrtf(bn_var[j] + BN_EPS);
            nd[j] = bn_gamma[j] * (h2v[j] - bn_mean[j]) * inv + bn_beta[j];
        }
        float acc = b2p[0];
#pragma unroll
        for (int m = 0; m < 4; ++m) {
            float s = b1p[m];
#pragma unroll
            for (int j = 0; j < HID; ++j) s = fmaf(nd[j], w1p[m * HID + j], s);
            s = fmaxf(s, 0.f);
            acc = fmaf(s, w2p[m], acc);
        }
        out[b] = acc;
    }
}

extern "C" void kernel_launch(void* const* d_in, const int* in_sizes, int n_in,
                              void* d_out, int out_size, void* d_ws, size_t ws_size,
                              hipStream_t stream) {
    const float* x        = (const float*)d_in[0];
    const float* Wih1     = (const float*)d_in[1];
    const float* Whh1     = (const float*)d_in[2];
    const float* bih1     = (const float*)d_in[3];
    const float* bhh1     = (const float*)d_in[4];
    const float* Wih2     = (const float*)d_in[5];
    const float* Whh2     = (const float*)d_in[6];
    const float* bih2     = (const float*)d_in[7];
    const float* bhh2     = (const float*)d_in[8];
    const float* bn_gamma = (const float*)d_in[9];
    const float* bn_beta  = (const float*)d_in[10];
    const float* bn_mean  = (const float*)d_in[11];
    const float* bn_var   = (const float*)d_in[12];
    const float* w1p      = (const float*)d_in[13];
    const float* b1p      = (const float*)d_in[14];
    const float* w2p      = (const float*)d_in[15];
    const float* b2p      = (const float*)d_in[16];
    float* out = (float*)d_out;

    const int B = in_sizes[0] / (T_SEQ * INPUT);   // 4096
    dim3 grid(B / 8), block(256);
    hipLaunchKernelGGL(lstm_forex_kernel, grid, block, 0, stream,
                       x, Wih1, Whh1, bih1, bhh1, Wih2, Whh2, bih2, bhh2,
                       bn_gamma, bn_beta, bn_mean, bn_var, w1p, b1p, w2p, b2p, out);
}

// Round 8
// 311.801 us; speedup vs baseline: 1.4041x; 1.1452x over previous
//
#include <hip/hip_runtime.h>

#define T_SEQ 512
#define INPUT 14
#define HID 8
#define TC 16
#define NCHUNK (T_SEQ / TC)
#define BN_EPS 1e-5f

typedef float v2f __attribute__((ext_vector_type(2)));

__device__ __forceinline__ float fast_exp2(float x) { return __builtin_amdgcn_exp2f(x); }
__device__ __forceinline__ float fast_rcp(float x)  { return __builtin_amdgcn_rcpf(x); }

// packed fp32 math (CDNA): one instruction, two FMAs per lane
__device__ __forceinline__ v2f pk_fma(v2f a, v2f b, v2f c) {
    v2f d;
    asm("v_pk_fma_f32 %0, %1, %2, %3" : "=v"(d) : "v"(a), "v"(b), "v"(c));
    return d;
}
__device__ __forceinline__ v2f pk_mul(v2f a, v2f b) {
    v2f d;
    asm("v_pk_mul_f32 %0, %1, %2" : "=v"(d) : "v"(a), "v"(b));
    return d;
}
__device__ __forceinline__ v2f pk_add(v2f a, v2f b) {
    v2f d;
    asm("v_pk_add_f32 %0, %1, %2" : "=v"(d) : "v"(a), "v"(b));
    return d;
}

// ds_swizzle (LDS crossbar): BitMode imm = xor<<10 | or<<5 | and
template <int IMM>
__device__ __forceinline__ float swz(float v) {
    return __int_as_float(__builtin_amdgcn_ds_swizzle(__float_as_int(v), IMM));
}

// DPP cross-lane ops (VALU pipe)
#define DPP_BC0  0x00   // quad_perm [0,0,0,0] : broadcast quad-lane 0 (gate i)
#define DPP_BC1  0x55   // quad_perm [1,1,1,1] : broadcast quad-lane 1 (gate f)
#define DPP_BC2  0xAA   // quad_perm [2,2,2,2] : broadcast quad-lane 2 (gate g)
#define DPP_BC3  0xFF   // quad_perm [3,3,3,3] : broadcast quad-lane 3 (gate o)
#define DPP_XOR8 0x128  // row_ror:8 : lane ^= 8 within 16-row
template <int CTRL>
__device__ __forceinline__ float dpp(float v) {
    return __int_as_float(__builtin_amdgcn_update_dpp(
        0, __float_as_int(v), CTRL, 0xF, 0xF, true));
}

// UNIT-MAJOR layout: lane(within 32) = unit*4 + type.
// Butterfly images of h over unit bits (lane bits 2..4), paired {h,x8},{x4,x12},
// {x16,x24},{x20,x28}: pair units are u^{0,2},{1,3},{4,6},{5,7}.
__device__ __forceinline__ void butterfly8v(float h, v2f (&hx)[4]) {
    float x8  = dpp<DPP_XOR8>(h);  // xor 8  (VALU)
    float x4  = swz<0x101F>(h);    // xor 4  (LDS crossbar)
    float x16 = swz<0x401F>(h);    // xor 16
    float x20 = swz<0x501F>(h);    // xor 20
    hx[0].x = h;   hx[0].y = x8;
    hx[1].x = x4;  hx[1].y = dpp<DPP_XOR8>(x4);   // xor 12
    hx[2].x = x16; hx[2].y = dpp<DPP_XOR8>(x16);  // xor 24
    hx[3].x = x20; hx[3].y = dpp<DPP_XOR8>(x20);  // xor 28
}

// ============================================================================
// TIME-SKEWED TWO-LAYER SCHEDULE (same lane layout as the 185us best kernel):
// Block: 256 threads = 4 waves; each wave = 2 batch elements (32 lanes each).
// Within 32 lanes: unit = (l5>>2)&7, type = l5&3 (0=i,1=f,2=g,3=o).
// Per wave-step s the body computes L1(t=s) AND L2(t=s-1):
//   - both gate dots are ready at body start (L2's p-dot reads hx1 = h1(s-1)
//     images BEFORE butterfly1 overwrites them)
//   - the two activation chains (exp2->rcp->...->exp2->rcp, ~200cy latency each)
//     are then INDEPENDENT, so the in-order wave can interleave them instead of
//     serializing them -- this is the identified ~500cy/step stall.
// Prologue: zero hx2/c2 after body 0 (its L2 output is garbage). Epilogue: one
// L2 drain step for t=511.
// Numerics: weights/biases pre-scaled by the lane's exp2 activation constant;
// cell state kept pre-scaled (C = -2.885*c) so tanh(c)=2*rcp(1+exp2(C))-1.
// ============================================================================
__global__ __launch_bounds__(256, 2)
void lstm_forex_kernel(const float* __restrict__ x,
                       const float* __restrict__ Wih1, const float* __restrict__ Whh1,
                       const float* __restrict__ bih1, const float* __restrict__ bhh1,
                       const float* __restrict__ Wih2, const float* __restrict__ Whh2,
                       const float* __restrict__ bih2, const float* __restrict__ bhh2,
                       const float* __restrict__ bn_gamma, const float* __restrict__ bn_beta,
                       const float* __restrict__ bn_mean, const float* __restrict__ bn_var,
                       const float* __restrict__ w1p, const float* __restrict__ b1p,
                       const float* __restrict__ w2p, const float* __restrict__ b2p,
                       float* __restrict__ out)
{
    __shared__ float xbuf[4][2][TC][16];   // [wave][elem][t][14 padded to 16]

    const int tid  = threadIdx.x;
    const int wave = tid >> 6;
    const int lane = tid & 63;
    const int grp  = lane >> 5;          // which of the wave's 2 batch elements
    const int l5   = lane & 31;
    const int u    = (l5 >> 2) & 7;      // unit
    const int type = l5 & 3;             // gate type
    const int row  = type * 8 + u;       // weight row (PyTorch i,f,g,o blocks)

    const int b = blockIdx.x * 8 + wave * 2 + grp;

    // exp2-domain activation constants; scale folded into weights below
    const float gateScale = (type == 2) ? -2.885390082f : -1.4426950408f;
    const float actMul    = (type == 2) ? -5.770780164f : 1.f;   // g-lane -> -2.885*tanh(g)
    const float actAdd    = (type == 2) ?  2.885390082f : 0.f;

    // ---- per-lane weight rows (pre-scaled); recurrent mats pre-permuted for XOR
    //      butterfly, paired to match the image pairs {0,2},{1,3},{4,6},{5,7} ----
    v2f wi1p[7], wh1v[4], wi2v[4], wh2v[4];
#pragma unroll
    for (int k = 0; k < 7; ++k) {
        wi1p[k].x = Wih1[row * INPUT + 2 * k]     * gateScale;
        wi1p[k].y = Wih1[row * INPUT + 2 * k + 1] * gateScale;
    }
    const int poff[4] = {0, 1, 4, 5};
#pragma unroll
    for (int p = 0; p < 4; ++p) {
        int j0 = u ^ poff[p], j1 = j0 ^ 2;
        wh1v[p].x = Whh1[row * HID + j0] * gateScale;
        wh1v[p].y = Whh1[row * HID + j1] * gateScale;
        wi2v[p].x = Wih2[row * HID + j0] * gateScale;
        wi2v[p].y = Wih2[row * HID + j1] * gateScale;
        wh2v[p].x = Whh2[row * HID + j0] * gateScale;
        wh2v[p].y = Whh2[row * HID + j1] * gateScale;
    }
    const float bsum1s = (bih1[row] + bhh1[row]) * gateScale;
    const float bsum2s = (bih2[row] + bhh2[row]) * gateScale;
    const v2f   bias1  = { bsum1s, 0.f };
    const v2f   bias2  = { bsum2s, 0.f };

    // ---- x staging: 448 dwords per wave-chunk (2 elems * 16 t * 14), 7 per lane ----
    const float* gptr[7];
    int loff[7];
#pragma unroll
    for (int it = 0; it < 7; ++it) {
        int d   = it * 64 + lane;       // coalesced flat dword index within wave-chunk
        int es  = d / 224;              // which elem
        int idx = d - es * 224;         // dword within elem's 16x14 chunk
        int tr  = idx / 14;
        int k   = idx - tr * 14;
        int bb  = blockIdx.x * 8 + wave * 2 + es;
        gptr[it] = x + (size_t)bb * (T_SEQ * INPUT) + idx;
        loff[it] = es * (TC * 16) + tr * 16 + k;   // padded LDS layout
    }

    v2f hx1[4], hx2[4];                 // paired butterfly images of h1, h2
    float c1 = 0.f, c2 = 0.f;           // PRE-SCALED cell states (C = -2.885*c)
#pragma unroll
    for (int p = 0; p < 4; ++p) { hx1[p] = (v2f){0.f, 0.f}; hx2[p] = (v2f){0.f, 0.f}; }

    // prefetch chunk 0
    float st[7];
#pragma unroll
    for (int it = 0; it < 7; ++it) { st[it] = *gptr[it]; gptr[it] += TC * INPUT; }

    float (*xw)[TC][16] = xbuf[wave];

    for (int c = 0; c < NCHUNK; ++c) {
        // stage chunk c into LDS (in-order DS per wave makes this visible to reads below)
#pragma unroll
        for (int it = 0; it < 7; ++it) ((float*)xw)[loff[it]] = st[it];
        // prefetch chunk c+1 while computing chunk c
        if (c + 1 < NCHUNK) {
#pragma unroll
            for (int it = 0; it < 7; ++it) { st[it] = *gptr[it]; gptr[it] += TC * INPUT; }
        }
        __builtin_amdgcn_wave_barrier();

        // ===== Phase A: batched x-projections for all 16 steps -> registers =====
        v2f xp0[TC], xp1[TC];
#pragma unroll
        for (int t = 0; t < TC; ++t) {
            const float* xrow = &xw[grp][t][0];
            float4 xa = *(const float4*)(xrow + 0);
            float4 xb = *(const float4*)(xrow + 4);
            float4 xc = *(const float4*)(xrow + 8);
            float2 xd = *(const float2*)(xrow + 12);
            v2f a0 = pk_fma((v2f){xa.x, xa.y}, wi1p[0], bias1);
            v2f a1 = pk_mul((v2f){xa.z, xa.w}, wi1p[1]);
            a0 = pk_fma((v2f){xb.x, xb.y}, wi1p[2], a0);
            a1 = pk_fma((v2f){xb.z, xb.w}, wi1p[3], a1);
            a0 = pk_fma((v2f){xc.x, xc.y}, wi1p[4], a0);
            a1 = pk_fma((v2f){xc.z, xc.w}, wi1p[5], a1);
            a0 = pk_fma((v2f){xd.x, xd.y}, wi1p[6], a0);
            xp0[t] = a0;
            xp1[t] = a1;
        }

        // ===== Phase B: skewed recurrence -- body s computes L1(s) and L2(s-1) =====
#pragma unroll
        for (int t = 0; t < TC; ++t) {
            // ---- L1 dot for step s (uses hx1 = h1(s-1) images) ----
            v2f sA = pk_fma(hx1[0], wh1v[0], xp0[t]);
            v2f sB = pk_fma(hx1[1], wh1v[1], xp1[t]);
            sA = pk_fma(hx1[2], wh1v[2], sA);
            sB = pk_fma(hx1[3], wh1v[3], sB);
            v2f sC = pk_add(sA, sB);
            float acc1 = sC.x + sC.y;

            // ---- L2 dot for step s-1 (hx2 = h2(s-2) images; hx1 = h1(s-1) images,
            //      read BEFORE butterfly1 overwrites them) ----
            v2f qA = pk_fma(hx2[0], wh2v[0], bias2);
            v2f qB = pk_mul(hx2[1], wh2v[1]);
            qA = pk_fma(hx2[2], wh2v[2], qA);
            qB = pk_fma(hx2[3], wh2v[3], qB);
            v2f pA = pk_fma(hx1[0], wi2v[0], qA);
            v2f pB = pk_fma(hx1[1], wi2v[1], qB);
            pA = pk_fma(hx1[2], wi2v[2], pA);
            pB = pk_fma(hx1[3], wi2v[3], pB);
            v2f pC = pk_add(pA, pB);
            float acc2 = pC.x + pC.y;

            // ---- two INDEPENDENT activation chains (compiler interleaves) ----
            float v0 = fmaf(fast_rcp(1.f + fast_exp2(acc1)), actMul, actAdd);
            float u0 = fmaf(fast_rcp(1.f + fast_exp2(acc2)), actMul, actAdd);

            float vi = dpp<DPP_BC0>(v0);
            float vf = dpp<DPP_BC1>(v0);
            float vg = dpp<DPP_BC2>(v0);   // = -2.885*tanh(g)
            float vo = dpp<DPP_BC3>(v0);
            c1 = fmaf(vf, c1, vi * vg);
            float th1 = fmaf(fast_rcp(1.f + fast_exp2(c1)), 2.f, -1.f);
            float h1u = vo * th1;          // h1(s)

            float ui = dpp<DPP_BC0>(u0);
            float uf = dpp<DPP_BC1>(u0);
            float ug = dpp<DPP_BC2>(u0);
            float uo = dpp<DPP_BC3>(u0);
            c2 = fmaf(uf, c2, ui * ug);
            float th2 = fmaf(fast_rcp(1.f + fast_exp2(c2)), 2.f, -1.f);
            float h2u = uo * th2;          // h2(s-1)

            butterfly8v(h1u, hx1);
            butterfly8v(h2u, hx2);

            // first body's L2 output is garbage (h2(-1) must be 0)
            if (c == 0 && t == 0) {
#pragma unroll
                for (int p = 0; p < 4; ++p) hx2[p] = (v2f){0.f, 0.f};
                c2 = 0.f;
            }
        }
    }

    // ---- epilogue drain: L2 for t=511 (hx1 = h1(511), hx2 = h2(510)) ----
    {
        v2f qA = pk_fma(hx2[0], wh2v[0], bias2);
        v2f qB = pk_mul(hx2[1], wh2v[1]);
        qA = pk_fma(hx2[2], wh2v[2], qA);
        qB = pk_fma(hx2[3], wh2v[3], qB);
        v2f pA = pk_fma(hx1[0], wi2v[0], qA);
        v2f pB = pk_fma(hx1[1], wi2v[1], qB);
        pA = pk_fma(hx1[2], wi2v[2], pA);
        pB = pk_fma(hx1[3], wi2v[3], pB);
        v2f pC = pk_add(pA, pB);
        float acc2 = pC.x + pC.y;

        float u0 = fmaf(fast_rcp(1.f + fast_exp2(acc2)), actMul, actAdd);
        float ui = dpp<DPP_BC0>(u0);
        float uf = dpp<DPP_BC1>(u0);
        float ug = dpp<DPP_BC2>(u0);
        float uo = dpp<DPP_BC3>(u0);
        c2 = fmaf(uf, c2, ui * ug);
        float th2 = fmaf(fast_rcp(1.f + fast_exp2(c2)), 2.f, -1.f);
        float h2u = uo * th2;              // h2(511)
        butterfly8v(h2u, hx2);
    }

    // ---- BN (eval) + MLP head, one lane per batch element ----
    // At l5==0 (u==0): pairs hold units {0,2},{1,3},{4,6},{5,7}.
    if (l5 == 0) {
        float h2v[HID];
        h2v[0] = hx2[0].x; h2v[2] = hx2[0].y;
        h2v[1] = hx2[1].x; h2v[3] = hx2[1].y;
        h2v[4] = hx2[2].x; h2v[6] = hx2[2].y;
        h2v[5] = hx2[3].x; h2v[7] = hx2[3].y;
        float nd[HID];
#pragma unroll
        for (int j = 0; j < HID; ++j) {
            float inv = 1.f / sqrtf(bn_var[j] + BN_EPS);
            nd[j] = bn_gamma[j] * (h2v[j] - bn_mean[j]) * inv + bn_beta[j];
        }
        float acc = b2p[0];
#pragma unroll
        for (int m = 0; m < 4; ++m) {
            float s = b1p[m];
#pragma unroll
            for (int j = 0; j < HID; ++j) s = fmaf(nd[j], w1p[m * HID + j], s);
            s = fmaxf(s, 0.f);
            acc = fmaf(s, w2p[m], acc);
        }
        out[b] = acc;
    }
}

extern "C" void kernel_launch(void* const* d_in, const int* in_sizes, int n_in,
                              void* d_out, int out_size, void* d_ws, size_t ws_size,
                              hipStream_t stream) {
    const float* x        = (const float*)d_in[0];
    const float* Wih1     = (const float*)d_in[1];
    const float* Whh1     = (const float*)d_in[2];
    const float* bih1     = (const float*)d_in[3];
    const float* bhh1     = (const float*)d_in[4];
    const float* Wih2     = (const float*)d_in[5];
    const float* Whh2     = (const float*)d_in[6];
    const float* bih2     = (const float*)d_in[7];
    const float* bhh2     = (const float*)d_in[8];
    const float* bn_gamma = (const float*)d_in[9];
    const float* bn_beta  = (const float*)d_in[10];
    const float* bn_mean  = (const float*)d_in[11];
    const float* bn_var   = (const float*)d_in[12];
    const float* w1p      = (const float*)d_in[13];
    const float* b1p      = (const float*)d_in[14];
    const float* w2p      = (const float*)d_in[15];
    const float* b2p      = (const float*)d_in[16];
    float* out = (float*)d_out;

    const int B = in_sizes[0] / (T_SEQ * INPUT);   // 4096
    dim3 grid(B / 8), block(256);
    hipLaunchKernelGGL(lstm_forex_kernel, grid, block, 0, stream,
                       x, Wih1, Whh1, bih1, bhh1, Wih2, Whh2, bih2, bhh2,
                       bn_gamma, bn_beta, bn_mean, bn_var, w1p, b1p, w2p, b2p, out);
}